// Round 16
// baseline (259.941 us; speedup 1.0000x reference)
//
#include <hip/hip_runtime.h>
#include <hip/hip_fp8.h>
#include <math.h>

// DrugEncoder: 2x TransformerConv (heads=1) + global mean pool.
// N=50000 nodes, E=800000 edges, G=512 graphs, D_IN=64, D_HID=D_EMB=128.
//
// R16: edge_agg -> 8 x 8-lane streams (16 dims/lane): ceil(deg/8) iterations,
//      3-level shfl reduce, f32x2 packed math (v_pk_fma_f32 target).
//      Rest = R15: fp8 kv 256B rows, bf16 skip, exp2-domain softmax,
//      atomic-free fill + interleaved gemm1, bf16 pool.

constexpr int D1 = 64;
constexpr int DH = 128;
constexpr int SCHUNK = 1024;
// (1/sqrt(128)) * log2(e): softmax done in exp2 domain
constexpr float QSCALE2 = 0.12751743f;

typedef __attribute__((ext_vector_type(8))) short short8v;
typedef __attribute__((ext_vector_type(4))) float f32x4;
typedef __attribute__((ext_vector_type(2))) float f32x2;

#if __has_builtin(__builtin_amdgcn_cvt_pk_f32_fp8)
#define HW_FP8_DEC 1
#endif

__device__ inline unsigned short bf16r(float f) {
  unsigned u = __float_as_uint(f);
  return (unsigned short)((u + 0x7fffu + ((u >> 16) & 1u)) >> 16);
}

__device__ inline unsigned pack_bf16_2(float a, float b) {
  return (unsigned)bf16r(a) | ((unsigned)bf16r(b) << 16);
}

__device__ inline float bf16f(unsigned short u) {
  return __uint_as_float(((unsigned)u) << 16);
}

__device__ inline f32x2 bf16_2f(unsigned u) {
  f32x2 r;
  r[0] = __uint_as_float(u << 16);
  r[1] = __uint_as_float(u & 0xffff0000u);
  return r;
}

__device__ inline unsigned char fp8e(float f) {
  __hip_fp8_e4m3 h(f);
  return h.__x;
}

#ifndef HW_FP8_DEC
__device__ inline float fp8f_sw(unsigned b) {
  unsigned e = (b >> 3) & 15u, mm = b & 7u;
  float v;
  if (e == 0) v = (float)mm * 0.001953125f;  // m * 2^-9
  else v = __uint_as_float(((e + 119u) << 23) | (mm << 20));
  return (b & 0x80u) ? -v : v;
}
#endif

// decode 4 fp8 (one dword) into two f32x2
__device__ inline void fp8_dec4(unsigned w, f32x2* lo, f32x2* hi) {
#ifdef HW_FP8_DEC
  *lo = __builtin_amdgcn_cvt_pk_f32_fp8((int)w, false);
  *hi = __builtin_amdgcn_cvt_pk_f32_fp8((int)w, true);
#else
  (*lo)[0] = fp8f_sw(w & 0xffu);
  (*lo)[1] = fp8f_sw((w >> 8) & 0xffu);
  (*hi)[0] = fp8f_sw((w >> 16) & 0xffu);
  (*hi)[1] = fp8f_sw(w >> 24);
#endif
}

// ---------------- level A: histogram(+ranks) + weight/x prep ----------------

__global__ __launch_bounds__(256) void hist_prep(
    const int* __restrict__ dst, int* __restrict__ deg, int* __restrict__ rank,
    int E, int nbHist,
    const float* w0, const float* w1, const float* w2, const float* w3,
    const float* w4, const float* w5, const float* w6, const float* w7,
    unsigned short* t0, unsigned short* t1, unsigned short* t2,
    unsigned short* t3, unsigned short* t4, unsigned short* t5,
    unsigned short* t6, unsigned short* t7,
    const float4* __restrict__ x, uint2* __restrict__ xb, int n4) {
  int b = blockIdx.x;
  int tid = threadIdx.x;
  if (b < nbHist) {
    int i = b * 256 + tid;
    if (i < (E >> 2)) {
      int4 d4 = ((const int4*)dst)[i];
      int4 r4;
      r4.x = atomicAdd(&deg[d4.x], 1);
      r4.y = atomicAdd(&deg[d4.y], 1);
      r4.z = atomicAdd(&deg[d4.z], 1);
      r4.w = atomicAdd(&deg[d4.w], 1);
      ((int4*)rank)[i] = r4;
    }
    if (b == 0 && tid == 0) {
      for (int e = E & ~3; e < E; ++e) rank[e] = atomicAdd(&deg[dst[e]], 1);
    }
    return;
  }
  int g = b - nbHist;
  if (g < 512) {
    int m = g >> 6, bx = g & 63;
    const float* W;
    unsigned short* T;
    switch (m) {
      case 0: W = w0; T = t0; break;
      case 1: W = w1; T = t1; break;
      case 2: W = w2; T = t2; break;
      case 3: W = w3; T = t3; break;
      case 4: W = w4; T = t4; break;
      case 5: W = w5; T = t5; break;
      case 6: W = w6; T = t6; break;
      default: W = w7; T = t7; break;
    }
    int din = (m < 4) ? 64 : 128;
    int total = din * 128;
    int i = bx * 256 + tid;
    if (i < total) {
      int r = i >> 7, c = i & 127;  // W[r][c]
      T[c * din + r] = bf16r(W[i]);
    }
    return;
  }
  int bx = g - 512;  // 256 blocks
  for (int i = bx * 256 + tid; i < n4; i += 256 * 256) {
    float4 v = x[i];
    uint2 o;
    o.x = pack_bf16_2(v.x, v.y);
    o.y = pack_bf16_2(v.z, v.w);
    xb[i] = o;
  }
}

// ---------------- CSR scan ----------------

__global__ void scan_chunks(const int* __restrict__ deg, int* __restrict__ incl,
                            int* __restrict__ sums, int N) {
  __shared__ int lds[256];
  int b = blockIdx.x, tid = threadIdx.x;
  int base = b * SCHUNK + tid * 4;
  int e0 = (base + 0 < N) ? deg[base + 0] : 0;
  int e1 = (base + 1 < N) ? deg[base + 1] : 0;
  int e2 = (base + 2 < N) ? deg[base + 2] : 0;
  int e3 = (base + 3 < N) ? deg[base + 3] : 0;
  int t0 = e0, t1 = t0 + e1, t2 = t1 + e2, t3 = t2 + e3;
  lds[tid] = t3;
  __syncthreads();
  for (int off = 1; off < 256; off <<= 1) {
    int v = (tid >= off) ? lds[tid - off] : 0;
    __syncthreads();
    lds[tid] += v;
    __syncthreads();
  }
  int excl = (tid > 0) ? lds[tid - 1] : 0;
  if (base + 0 < N) incl[base + 0] = t0 + excl;
  if (base + 1 < N) incl[base + 1] = t1 + excl;
  if (base + 2 < N) incl[base + 2] = t2 + excl;
  if (base + 3 < N) incl[base + 3] = t3 + excl;
  if (tid == 255) sums[b] = lds[255];
}

__global__ void finalize_rowptr(const int* __restrict__ incl, const int* __restrict__ sums,
                                int* __restrict__ rowptr, int N) {
  int n = blockIdx.x * blockDim.x + threadIdx.x;
  if (n < N) {
    int ch = n / SCHUNK;
    int off = 0;
    for (int i = 0; i < ch; ++i) off += sums[i];
    rowptr[n + 1] = incl[n] + off;
  }
  if (n == 0) rowptr[0] = 0;
}

// ---------------- bf16 MFMA 4-way linear (tile body) ----------------
// y: 0=q(bf16, pre-scaled by (1/sqrt(128))*log2e) 1=k(fp8 -> kv[0..128))
// 2=v(fp8 -> kv[128..256)) 3=skip(bf16). 8 waves 2x4: wave = 64 rows x 32 cols.

template <int DIN>
__device__ __forceinline__ void gemm4_tile(
    int bx, int y, int tid,
    const unsigned short* __restrict__ xb, int N,
    const unsigned short* __restrict__ Wt0, const float* __restrict__ B0,
    const unsigned short* __restrict__ Wt1, const float* __restrict__ B1,
    const unsigned short* __restrict__ Wt2, const float* __restrict__ B2,
    const unsigned short* __restrict__ Wt3, const float* __restrict__ B3,
    unsigned short* __restrict__ Qb, unsigned char* __restrict__ KV,
    unsigned short* __restrict__ Os) {
  constexpr int DS = DIN + 8;
  __shared__ __align__(16) unsigned short As[128 * DS];
  __shared__ __align__(16) unsigned short Bs[128 * DS];
  const unsigned short* Wt;
  const float* Bias;
  switch (y) {
    case 0: Wt = Wt0; Bias = B0; break;
    case 1: Wt = Wt1; Bias = B1; break;
    case 2: Wt = Wt2; Bias = B2; break;
    default: Wt = Wt3; Bias = B3; break;
  }
  int n0 = bx * 128;

  constexpr int CPR = DIN / 8;
  constexpr int ACH = 128 * CPR;
#pragma unroll
  for (int c = tid; c < ACH; c += 512) {
    int row = c / CPR, c8 = c - row * CPR;
    int n = n0 + row;
    uint4 val = {0u, 0u, 0u, 0u};
    if (n < N) val = *(const uint4*)&xb[(size_t)n * DIN + c8 * 8];
    *(uint4*)&As[row * DS + c8 * 8] = val;
  }
#pragma unroll
  for (int c = tid; c < ACH; c += 512) {
    int row = c / CPR, c8 = c - row * CPR;
    uint4 val = *(const uint4*)&Wt[(size_t)row * DIN + c8 * 8];
    *(uint4*)&Bs[row * DS + c8 * 8] = val;
  }
  __syncthreads();

  int w = tid >> 6, lane = tid & 63, lr = lane & 15, lg = lane >> 4;
  int wr = w >> 2;
  int wc = w & 3;
  constexpr int KS = DIN / 32;

  short8v a[4][KS];
#pragma unroll
  for (int af = 0; af < 4; ++af)
#pragma unroll
    for (int ks = 0; ks < KS; ++ks)
      a[af][ks] = *(const short8v*)&As[(wr * 64 + af * 16 + lr) * DS + ks * 32 + lg * 8];

  f32x4 acc[4][2];
#pragma unroll
  for (int af = 0; af < 4; ++af)
#pragma unroll
    for (int nf = 0; nf < 2; ++nf) acc[af][nf] = (f32x4){0.f, 0.f, 0.f, 0.f};

#pragma unroll
  for (int ks = 0; ks < KS; ++ks) {
#pragma unroll
    for (int nf = 0; nf < 2; ++nf) {
      short8v b = *(const short8v*)&Bs[(wc * 32 + nf * 16 + lr) * DS + ks * 32 + lg * 8];
#pragma unroll
      for (int af = 0; af < 4; ++af)
        acc[af][nf] = __builtin_amdgcn_mfma_f32_16x16x32_bf16(a[af][ks], b, acc[af][nf], 0, 0, 0);
    }
  }

#pragma unroll
  for (int af = 0; af < 4; ++af) {
    int rbase = n0 + wr * 64 + af * 16 + lg * 4;
#pragma unroll
    for (int nf = 0; nf < 2; ++nf) {
      int col = wc * 32 + nf * 16 + lr;
      float bias = Bias[col];
      if (y == 0) {
#pragma unroll
        for (int r = 0; r < 4; ++r) {
          int n = rbase + r;
          if (n < N) Qb[(size_t)n * 128 + col] = bf16r((acc[af][nf][r] + bias) * QSCALE2);
        }
      } else if (y == 1) {
#pragma unroll
        for (int r = 0; r < 4; ++r) {
          int n = rbase + r;
          if (n < N) KV[(size_t)n * 256 + col] = fp8e(acc[af][nf][r] + bias);
        }
      } else if (y == 2) {
#pragma unroll
        for (int r = 0; r < 4; ++r) {
          int n = rbase + r;
          if (n < N) KV[(size_t)n * 256 + 128 + col] = fp8e(acc[af][nf][r] + bias);
        }
      } else {
#pragma unroll
        for (int r = 0; r < 4; ++r) {
          int n = rbase + r;
          if (n < N) Os[(size_t)n * 128 + col] = bf16r(acc[af][nf][r] + bias);
        }
      }
    }
  }
}

// ---------------- level D: fill_csr + layer-1 gemm, interleaved ----------------

template <int DIN>
__global__ __launch_bounds__(512) void fill_gemm1(
    const int* __restrict__ src, const int* __restrict__ dst,
    const int* __restrict__ rank, const int* __restrict__ rowptr,
    int* __restrict__ csr_src, int E, int epb4,
    const unsigned short* __restrict__ xb, int N,
    const unsigned short* __restrict__ Wt0, const float* __restrict__ B0,
    const unsigned short* __restrict__ Wt1, const float* __restrict__ B1,
    const unsigned short* __restrict__ Wt2, const float* __restrict__ B2,
    const unsigned short* __restrict__ Wt3, const float* __restrict__ B3,
    unsigned short* __restrict__ Qb, unsigned char* __restrict__ KV,
    unsigned short* __restrict__ Os) {
  int b = blockIdx.x;
  int b5 = b / 5, r5 = b - b5 * 5;
  if (r5 == 0) {
    int e4 = E >> 2;
    int end = min((b5 + 1) * epb4, e4);
    for (int i = b5 * epb4 + threadIdx.x; i < end; i += 512) {
      int4 d4 = ((const int4*)dst)[i];
      int4 r4 = ((const int4*)rank)[i];
      int4 s4 = ((const int4*)src)[i];
      csr_src[rowptr[d4.x] + r4.x] = s4.x;
      csr_src[rowptr[d4.y] + r4.y] = s4.y;
      csr_src[rowptr[d4.z] + r4.z] = s4.z;
      csr_src[rowptr[d4.w] + r4.w] = s4.w;
    }
    if (b5 == 0 && threadIdx.x == 0) {
      for (int e = E & ~3; e < E; ++e) csr_src[rowptr[dst[e]] + rank[e]] = src[e];
    }
    return;
  }
  int g = b5 * 4 + r5 - 1;
  gemm4_tile<DIN>(g >> 2, g & 3, threadIdx.x, xb, N, Wt0, B0, Wt1, B1,
                  Wt2, B2, Wt3, B3, Qb, KV, Os);
}

template <int DIN>
__global__ __launch_bounds__(512) void gemm4(
    const unsigned short* __restrict__ xb, int N,
    const unsigned short* __restrict__ Wt0, const float* __restrict__ B0,
    const unsigned short* __restrict__ Wt1, const float* __restrict__ B1,
    const unsigned short* __restrict__ Wt2, const float* __restrict__ B2,
    const unsigned short* __restrict__ Wt3, const float* __restrict__ B3,
    unsigned short* __restrict__ Qb, unsigned char* __restrict__ KV,
    unsigned short* __restrict__ Os) {
  gemm4_tile<DIN>(blockIdx.x, blockIdx.y, threadIdx.x, xb, N, Wt0, B0, Wt1, B1,
                  Wt2, B2, Wt3, B3, Qb, KV, Os);
}

// ---------------- edge aggregation: 8 x 8-lane streams, exp2 domain ---------
// Wave = 1 node. Stream g8 = lane>>3 handles edges e = beg+g8+8*it; sublane
// sl = lane&7 owns dims [16*sl, 16*sl+16). Dot reduce = 3 shfl levels.
// f32x2 packed math throughout (v_pk_fma_f32). Deferred-max slack 8 (log2).
// Merges ^8, ^16, ^32; m init -1e30 (NaN-safe).
// kv row 256B: k fp8 [0,128), v fp8 [128,256). skip bf16; q bf16 pre-scaled.

template <bool RELU>
__global__ __launch_bounds__(256) void edge_agg8(
    const unsigned short* __restrict__ qb, const unsigned char* __restrict__ kv,
    const int* __restrict__ rowptr, const int* __restrict__ csr_src,
    const unsigned short* __restrict__ skipb, unsigned short* __restrict__ outp,
    int N) {
  int tid = threadIdx.x;
  int lane = tid & 63;
  int wv = tid >> 6;
  int n = blockIdx.x * 4 + wv;
  if (n >= N) return;
  int g8 = lane >> 3;
  int sl = lane & 7;
  // q: 16 bf16 at dim offset 16*sl
  uint4 qa = *(const uint4*)&qb[(size_t)n * 128 + 16 * sl];
  uint4 qc = *(const uint4*)&qb[(size_t)n * 128 + 16 * sl + 8];
  f32x2 q2[8];
  q2[0] = bf16_2f(qa.x); q2[1] = bf16_2f(qa.y);
  q2[2] = bf16_2f(qa.z); q2[3] = bf16_2f(qa.w);
  q2[4] = bf16_2f(qc.x); q2[5] = bf16_2f(qc.y);
  q2[6] = bf16_2f(qc.z); q2[7] = bf16_2f(qc.w);
  int beg = rowptr[n];
  int deg = rowptr[n + 1] - beg;
  float m = -1e30f, lsum = 0.f;
  f32x2 acc2[8];
#pragma unroll
  for (int j = 0; j < 8; ++j) acc2[j] = (f32x2){0.f, 0.f};
  int cnt = (deg - g8 + 7) >> 3;  // >=0 since deg>=0, g8<=7
  const int* cp = csr_src + beg + g8;
  unsigned ko = 16u * sl, vo = 128u + 16u * sl;
  uint4 k0 = {0, 0, 0, 0}, k1 = {0, 0, 0, 0};
  uint4 v0 = {0, 0, 0, 0}, v1 = {0, 0, 0, 0};
  if (cnt >= 1) {
    unsigned r = (unsigned)cp[0] * 256u;
    k0 = *(const uint4*)(kv + r + ko);
    v0 = *(const uint4*)(kv + r + vo);
  }
  if (cnt >= 2) {
    unsigned r = (unsigned)cp[8] * 256u;
    k1 = *(const uint4*)(kv + r + ko);
    v1 = *(const uint4*)(kv + r + vo);
  }
  for (int it = 0; it < cnt; ++it) {
    uint4 kc = k0;
    uint4 vc = v0;
    k0 = k1;
    v0 = v1;
    if (it + 2 < cnt) {
      unsigned r = (unsigned)cp[8 * (it + 2)] * 256u;
      k1 = *(const uint4*)(kv + r + ko);
      v1 = *(const uint4*)(kv + r + vo);
    }
    f32x2 kd[8];
    fp8_dec4(kc.x, &kd[0], &kd[1]);
    fp8_dec4(kc.y, &kd[2], &kd[3]);
    fp8_dec4(kc.z, &kd[4], &kd[5]);
    fp8_dec4(kc.w, &kd[6], &kd[7]);
    f32x2 d2 = q2[0] * kd[0];
#pragma unroll
    for (int j = 1; j < 8; ++j) d2 += q2[j] * kd[j];
    float d = d2[0] + d2[1];
#pragma unroll
    for (int off = 1; off < 8; off <<= 1) d += __shfl_xor(d, off);
    f32x2 w2[8];
    fp8_dec4(vc.x, &w2[0], &w2[1]);
    fp8_dec4(vc.y, &w2[2], &w2[3]);
    fp8_dec4(vc.z, &w2[4], &w2[5]);
    fp8_dec4(vc.w, &w2[6], &w2[7]);
    if (d > m + 8.f) {        // rare: new max beyond slack -> rescale
      float cf = exp2f(m - d);
      f32x2 cf2 = {cf, cf};
      lsum = lsum * cf + 1.f;
#pragma unroll
      for (int j = 0; j < 8; ++j) acc2[j] = acc2[j] * cf2 + w2[j];
      m = d;
    } else {                  // common: accumulate against stale max
      float ef = exp2f(d - m);
      f32x2 ef2 = {ef, ef};
      lsum += ef;
#pragma unroll
      for (int j = 0; j < 8; ++j) acc2[j] += ef2 * w2[j];
    }
  }
  // merge 8 stream states: ^8, ^16, ^32 (m=-1e30 keeps empty streams NaN-free)
#pragma unroll
  for (int ofs = 8; ofs <= 32; ofs <<= 1) {
    float mo = __shfl_xor(m, ofs);
    float lo = __shfl_xor(lsum, ofs);
    f32x2 ao[8];
#pragma unroll
    for (int j = 0; j < 8; ++j) {
      ao[j][0] = __shfl_xor(acc2[j][0], ofs);
      ao[j][1] = __shfl_xor(acc2[j][1], ofs);
    }
    float M = fmaxf(m, mo);
    float c1 = exp2f(m - M);
    float c2 = exp2f(mo - M);
    f32x2 c12 = {c1, c1}, c22 = {c2, c2};
    lsum = lsum * c1 + lo * c2;
#pragma unroll
    for (int j = 0; j < 8; ++j) acc2[j] = acc2[j] * c12 + ao[j] * c22;
    m = M;
  }
  if (lane < 8) {
    float rl = (deg > 0) ? 1.f / (lsum + 1e-16f) : 0.f;
    uint4 sa = *(const uint4*)&skipb[(size_t)n * 128 + 16 * sl];
    uint4 sc = *(const uint4*)&skipb[(size_t)n * 128 + 16 * sl + 8];
    unsigned sw[8] = {sa.x, sa.y, sa.z, sa.w, sc.x, sc.y, sc.z, sc.w};
    unsigned ow[8];
#pragma unroll
    for (int j = 0; j < 8; ++j) {
      f32x2 s2 = bf16_2f(sw[j]);
      float oa = s2[0] + acc2[j][0] * rl;
      float ob = s2[1] + acc2[j][1] * rl;
      if (RELU) {
        oa = fmaxf(oa, 0.f);
        ob = fmaxf(ob, 0.f);
      }
      ow[j] = pack_bf16_2(oa, ob);
    }
    uint4 p0 = {ow[0], ow[1], ow[2], ow[3]};
    uint4 p1 = {ow[4], ow[5], ow[6], ow[7]};
    *(uint4*)&outp[(size_t)n * 128 + 16 * sl] = p0;
    *(uint4*)&outp[(size_t)n * 128 + 16 * sl + 8] = p1;
  }
}

// ---------------- global mean pool (batch sorted, bf16 input) ----------------

__global__ __launch_bounds__(128) void pool_kernel(const unsigned short* __restrict__ h,
                                                   const int* __restrict__ batch,
                                                   float* __restrict__ out, int N) {
  int g = blockIdx.x;
  int lo = 0, hi = N;
  while (lo < hi) { int mid = (lo + hi) >> 1; if (batch[mid] < g) lo = mid + 1; else hi = mid; }
  int s0 = lo;
  hi = N;
  while (lo < hi) { int mid = (lo + hi) >> 1; if (batch[mid] <= g) lo = mid + 1; else hi = mid; }
  int s1 = lo;
  int j = threadIdx.x;
  float acc = 0.f;
  for (int n = s0; n < s1; ++n) acc += bf16f(h[(size_t)n * 128 + j]);
  out[(size_t)g * 128 + j] = acc / fmaxf((float)(s1 - s0), 1.f);
}

// ---------------- launch ----------------

extern "C" void kernel_launch(void* const* d_in, const int* in_sizes, int n_in,
                              void* d_out, int out_size, void* d_ws, size_t ws_size,
                              hipStream_t stream) {
  const float* x = (const float*)d_in[0];
  const int* ei = (const int*)d_in[1];
  const int* batch = (const int*)d_in[2];
  const float* Wq1 = (const float*)d_in[3];
  const float* bq1 = (const float*)d_in[4];
  const float* Wk1 = (const float*)d_in[5];
  const float* bk1 = (const float*)d_in[6];
  const float* Wv1 = (const float*)d_in[7];
  const float* bv1 = (const float*)d_in[8];
  const float* Ws1 = (const float*)d_in[9];
  const float* bs1 = (const float*)d_in[10];
  const float* Wq2 = (const float*)d_in[11];
  const float* bq2 = (const float*)d_in[12];
  const float* Wk2 = (const float*)d_in[13];
  const float* bk2 = (const float*)d_in[14];
  const float* Wv2 = (const float*)d_in[15];
  const float* bv2 = (const float*)d_in[16];
  const float* Ws2 = (const float*)d_in[17];
  const float* bs2 = (const float*)d_in[18];

  int N = in_sizes[0] / D1;  // 50000
  int E = in_sizes[1] / 2;   // 800000
  int NG = out_size / DH;    // 512
  const int* src = ei;
  const int* dst = ei + E;

  char* ws = (char*)d_ws;
  unsigned short* qb = (unsigned short*)ws;  ws += (size_t)N * DH * 2;   // bf16 q (pre-scaled)
  unsigned char* kvb = (unsigned char*)ws;   ws += (size_t)N * 256;     // k fp8 | v fp8
  ws = (char*)(((size_t)ws + 255) & ~(size_t)255);
  unsigned short* sb = (unsigned short*)ws;  ws += (size_t)N * DH * 2;  // bf16 skip
  unsigned short* h1b = (unsigned short*)ws; ws += (size_t)N * DH * 2;  // bf16 h1 / h2
  unsigned short* xb = (unsigned short*)ws;  ws += (size_t)N * D1 * 2;  // bf16 x
  unsigned short* wt[8];
  for (int m = 0; m < 8; ++m) {
    int din = (m < 4) ? 64 : 128;
    wt[m] = (unsigned short*)ws;
    ws += (size_t)128 * din * 2;
  }
  ws = (char*)(((size_t)ws + 255) & ~(size_t)255);
  int* rowptr = (int*)ws; ws += (size_t)(N + 1) * 4;
  ws = (char*)(((size_t)ws + 255) & ~(size_t)255);
  int* deg = (int*)ws;  ws += (size_t)N * 4;
  int* incl = (int*)ws; ws += (size_t)N * 4;
  int* sums = (int*)ws; ws += 1024;
  int* rank = (int*)ws; ws += (size_t)E * 4;
  int* csr = (int*)ws;  ws += (size_t)E * 4;

  int nch = (N + SCHUNK - 1) / SCHUNK;
  int nbHist = ((E >> 2) + 255) / 256;
  int nb = (N + 127) / 128;           // gemm tiles (x4 y)
  int epb4 = ((E >> 2) + nb - 1) / nb;  // int4 edges per fill block

  hipMemsetAsync(deg, 0, (size_t)N * 4, stream);

  // level A: histogram+ranks + weight/x prep (one dispatch)
  hist_prep<<<nbHist + 768, 256, 0, stream>>>(
      dst, deg, rank, E, nbHist, Wq1, Wk1, Wv1, Ws1, Wq2, Wk2, Wv2, Ws2,
      wt[0], wt[1], wt[2], wt[3], wt[4], wt[5], wt[6], wt[7],
      (const float4*)x, (uint2*)xb, N * D1 / 4);
  scan_chunks<<<nch, 256, 0, stream>>>(deg, incl, sums, N);
  finalize_rowptr<<<(N + 255) / 256, 256, 0, stream>>>(incl, sums, rowptr, N);
  // level D: CSR fill + layer-1 gemm, block-interleaved 1:4
  fill_gemm1<D1><<<nb * 5, 512, 0, stream>>>(
      src, dst, rank, rowptr, csr, E, epb4, xb, N,
      wt[0], bq1, wt[1], bk1, wt[2], bv1, wt[3], bs1, qb, kvb, sb);
  edge_agg8<true><<<(N + 3) / 4, 256, 0, stream>>>(
      qb, kvb, rowptr, csr, sb, h1b, N);
  // layer 2
  gemm4<DH><<<dim3(nb, 4), 512, 0, stream>>>(h1b, N, wt[4], bq2, wt[5], bk2,
                                             wt[6], bv2, wt[7], bs2, qb, kvb, sb);
  edge_agg8<false><<<(N + 3) / 4, 256, 0, stream>>>(
      qb, kvb, rowptr, csr, sb, h1b, N);
  // mean pool (bf16 input)
  pool_kernel<<<NG, 128, 0, stream>>>(h1b, batch, (float*)d_out, N);
}

// Round 18
// 239.062 us; speedup vs baseline: 1.0873x; 1.0873x over previous
//
#include <hip/hip_runtime.h>
#include <hip/hip_fp8.h>
#include <math.h>

// DrugEncoder: 2x TransformerConv (heads=1) + global mean pool.
// N=50000 nodes, E=800000 edges, G=512 graphs, D_IN=64, D_HID=D_EMB=128.
//
// R17: revert to R15's edge_agg4 (4x16-lane streams, depth-2 prefetch,
//      occupancy-friendly) + f32x2 packed math only (R16's restructure hurt
//      occupancy; its packed math was the good half). Rest = R15.

constexpr int D1 = 64;
constexpr int DH = 128;
constexpr int SCHUNK = 1024;
// (1/sqrt(128)) * log2(e): softmax done in exp2 domain
constexpr float QSCALE2 = 0.12751743f;

typedef __attribute__((ext_vector_type(8))) short short8v;
typedef __attribute__((ext_vector_type(4))) float f32x4;
typedef __attribute__((ext_vector_type(2))) float f32x2;

#if __has_builtin(__builtin_amdgcn_cvt_pk_f32_fp8)
#define HW_FP8_DEC 1
#endif

__device__ inline unsigned short bf16r(float f) {
  unsigned u = __float_as_uint(f);
  return (unsigned short)((u + 0x7fffu + ((u >> 16) & 1u)) >> 16);
}

__device__ inline unsigned pack_bf16_2(float a, float b) {
  return (unsigned)bf16r(a) | ((unsigned)bf16r(b) << 16);
}

__device__ inline float bf16f(unsigned short u) {
  return __uint_as_float(((unsigned)u) << 16);
}

__device__ inline f32x2 bf16_2f(unsigned u) {
  f32x2 r;
  r[0] = __uint_as_float(u << 16);
  r[1] = __uint_as_float(u & 0xffff0000u);
  return r;
}

__device__ inline unsigned char fp8e(float f) {
  __hip_fp8_e4m3 h(f);
  return h.__x;
}

#ifndef HW_FP8_DEC
__device__ inline float fp8f_sw(unsigned b) {
  unsigned e = (b >> 3) & 15u, mm = b & 7u;
  float v;
  if (e == 0) v = (float)mm * 0.001953125f;  // m * 2^-9
  else v = __uint_as_float(((e + 119u) << 23) | (mm << 20));
  return (b & 0x80u) ? -v : v;
}
#endif

// decode 4 fp8 (one dword) into two f32x2
__device__ inline void fp8_dec4(unsigned w, f32x2* lo, f32x2* hi) {
#ifdef HW_FP8_DEC
  *lo = __builtin_amdgcn_cvt_pk_f32_fp8((int)w, false);
  *hi = __builtin_amdgcn_cvt_pk_f32_fp8((int)w, true);
#else
  (*lo)[0] = fp8f_sw(w & 0xffu);
  (*lo)[1] = fp8f_sw((w >> 8) & 0xffu);
  (*hi)[0] = fp8f_sw((w >> 16) & 0xffu);
  (*hi)[1] = fp8f_sw(w >> 24);
#endif
}

// ---------------- level A: histogram(+ranks) + weight/x prep ----------------

__global__ __launch_bounds__(256) void hist_prep(
    const int* __restrict__ dst, int* __restrict__ deg, int* __restrict__ rank,
    int E, int nbHist,
    const float* w0, const float* w1, const float* w2, const float* w3,
    const float* w4, const float* w5, const float* w6, const float* w7,
    unsigned short* t0, unsigned short* t1, unsigned short* t2,
    unsigned short* t3, unsigned short* t4, unsigned short* t5,
    unsigned short* t6, unsigned short* t7,
    const float4* __restrict__ x, uint2* __restrict__ xb, int n4) {
  int b = blockIdx.x;
  int tid = threadIdx.x;
  if (b < nbHist) {
    int i = b * 256 + tid;
    if (i < (E >> 2)) {
      int4 d4 = ((const int4*)dst)[i];
      int4 r4;
      r4.x = atomicAdd(&deg[d4.x], 1);
      r4.y = atomicAdd(&deg[d4.y], 1);
      r4.z = atomicAdd(&deg[d4.z], 1);
      r4.w = atomicAdd(&deg[d4.w], 1);
      ((int4*)rank)[i] = r4;
    }
    if (b == 0 && tid == 0) {
      for (int e = E & ~3; e < E; ++e) rank[e] = atomicAdd(&deg[dst[e]], 1);
    }
    return;
  }
  int g = b - nbHist;
  if (g < 512) {
    int m = g >> 6, bx = g & 63;
    const float* W;
    unsigned short* T;
    switch (m) {
      case 0: W = w0; T = t0; break;
      case 1: W = w1; T = t1; break;
      case 2: W = w2; T = t2; break;
      case 3: W = w3; T = t3; break;
      case 4: W = w4; T = t4; break;
      case 5: W = w5; T = t5; break;
      case 6: W = w6; T = t6; break;
      default: W = w7; T = t7; break;
    }
    int din = (m < 4) ? 64 : 128;
    int total = din * 128;
    int i = bx * 256 + tid;
    if (i < total) {
      int r = i >> 7, c = i & 127;  // W[r][c]
      T[c * din + r] = bf16r(W[i]);
    }
    return;
  }
  int bx = g - 512;  // 256 blocks
  for (int i = bx * 256 + tid; i < n4; i += 256 * 256) {
    float4 v = x[i];
    uint2 o;
    o.x = pack_bf16_2(v.x, v.y);
    o.y = pack_bf16_2(v.z, v.w);
    xb[i] = o;
  }
}

// ---------------- CSR scan ----------------

__global__ void scan_chunks(const int* __restrict__ deg, int* __restrict__ incl,
                            int* __restrict__ sums, int N) {
  __shared__ int lds[256];
  int b = blockIdx.x, tid = threadIdx.x;
  int base = b * SCHUNK + tid * 4;
  int e0 = (base + 0 < N) ? deg[base + 0] : 0;
  int e1 = (base + 1 < N) ? deg[base + 1] : 0;
  int e2 = (base + 2 < N) ? deg[base + 2] : 0;
  int e3 = (base + 3 < N) ? deg[base + 3] : 0;
  int t0 = e0, t1 = t0 + e1, t2 = t1 + e2, t3 = t2 + e3;
  lds[tid] = t3;
  __syncthreads();
  for (int off = 1; off < 256; off <<= 1) {
    int v = (tid >= off) ? lds[tid - off] : 0;
    __syncthreads();
    lds[tid] += v;
    __syncthreads();
  }
  int excl = (tid > 0) ? lds[tid - 1] : 0;
  if (base + 0 < N) incl[base + 0] = t0 + excl;
  if (base + 1 < N) incl[base + 1] = t1 + excl;
  if (base + 2 < N) incl[base + 2] = t2 + excl;
  if (base + 3 < N) incl[base + 3] = t3 + excl;
  if (tid == 255) sums[b] = lds[255];
}

__global__ void finalize_rowptr(const int* __restrict__ incl, const int* __restrict__ sums,
                                int* __restrict__ rowptr, int N) {
  int n = blockIdx.x * blockDim.x + threadIdx.x;
  if (n < N) {
    int ch = n / SCHUNK;
    int off = 0;
    for (int i = 0; i < ch; ++i) off += sums[i];
    rowptr[n + 1] = incl[n] + off;
  }
  if (n == 0) rowptr[0] = 0;
}

// ---------------- bf16 MFMA 4-way linear (tile body) ----------------
// y: 0=q(bf16, pre-scaled by (1/sqrt(128))*log2e) 1=k(fp8 -> kv[0..128))
// 2=v(fp8 -> kv[128..256)) 3=skip(bf16). 8 waves 2x4: wave = 64 rows x 32 cols.

template <int DIN>
__device__ __forceinline__ void gemm4_tile(
    int bx, int y, int tid,
    const unsigned short* __restrict__ xb, int N,
    const unsigned short* __restrict__ Wt0, const float* __restrict__ B0,
    const unsigned short* __restrict__ Wt1, const float* __restrict__ B1,
    const unsigned short* __restrict__ Wt2, const float* __restrict__ B2,
    const unsigned short* __restrict__ Wt3, const float* __restrict__ B3,
    unsigned short* __restrict__ Qb, unsigned char* __restrict__ KV,
    unsigned short* __restrict__ Os) {
  constexpr int DS = DIN + 8;
  __shared__ __align__(16) unsigned short As[128 * DS];
  __shared__ __align__(16) unsigned short Bs[128 * DS];
  const unsigned short* Wt;
  const float* Bias;
  switch (y) {
    case 0: Wt = Wt0; Bias = B0; break;
    case 1: Wt = Wt1; Bias = B1; break;
    case 2: Wt = Wt2; Bias = B2; break;
    default: Wt = Wt3; Bias = B3; break;
  }
  int n0 = bx * 128;

  constexpr int CPR = DIN / 8;
  constexpr int ACH = 128 * CPR;
#pragma unroll
  for (int c = tid; c < ACH; c += 512) {
    int row = c / CPR, c8 = c - row * CPR;
    int n = n0 + row;
    uint4 val = {0u, 0u, 0u, 0u};
    if (n < N) val = *(const uint4*)&xb[(size_t)n * DIN + c8 * 8];
    *(uint4*)&As[row * DS + c8 * 8] = val;
  }
#pragma unroll
  for (int c = tid; c < ACH; c += 512) {
    int row = c / CPR, c8 = c - row * CPR;
    uint4 val = *(const uint4*)&Wt[(size_t)row * DIN + c8 * 8];
    *(uint4*)&Bs[row * DS + c8 * 8] = val;
  }
  __syncthreads();

  int w = tid >> 6, lane = tid & 63, lr = lane & 15, lg = lane >> 4;
  int wr = w >> 2;
  int wc = w & 3;
  constexpr int KS = DIN / 32;

  short8v a[4][KS];
#pragma unroll
  for (int af = 0; af < 4; ++af)
#pragma unroll
    for (int ks = 0; ks < KS; ++ks)
      a[af][ks] = *(const short8v*)&As[(wr * 64 + af * 16 + lr) * DS + ks * 32 + lg * 8];

  f32x4 acc[4][2];
#pragma unroll
  for (int af = 0; af < 4; ++af)
#pragma unroll
    for (int nf = 0; nf < 2; ++nf) acc[af][nf] = (f32x4){0.f, 0.f, 0.f, 0.f};

#pragma unroll
  for (int ks = 0; ks < KS; ++ks) {
#pragma unroll
    for (int nf = 0; nf < 2; ++nf) {
      short8v b = *(const short8v*)&Bs[(wc * 32 + nf * 16 + lr) * DS + ks * 32 + lg * 8];
#pragma unroll
      for (int af = 0; af < 4; ++af)
        acc[af][nf] = __builtin_amdgcn_mfma_f32_16x16x32_bf16(a[af][ks], b, acc[af][nf], 0, 0, 0);
    }
  }

#pragma unroll
  for (int af = 0; af < 4; ++af) {
    int rbase = n0 + wr * 64 + af * 16 + lg * 4;
#pragma unroll
    for (int nf = 0; nf < 2; ++nf) {
      int col = wc * 32 + nf * 16 + lr;
      float bias = Bias[col];
      if (y == 0) {
#pragma unroll
        for (int r = 0; r < 4; ++r) {
          int n = rbase + r;
          if (n < N) Qb[(size_t)n * 128 + col] = bf16r((acc[af][nf][r] + bias) * QSCALE2);
        }
      } else if (y == 1) {
#pragma unroll
        for (int r = 0; r < 4; ++r) {
          int n = rbase + r;
          if (n < N) KV[(size_t)n * 256 + col] = fp8e(acc[af][nf][r] + bias);
        }
      } else if (y == 2) {
#pragma unroll
        for (int r = 0; r < 4; ++r) {
          int n = rbase + r;
          if (n < N) KV[(size_t)n * 256 + 128 + col] = fp8e(acc[af][nf][r] + bias);
        }
      } else {
#pragma unroll
        for (int r = 0; r < 4; ++r) {
          int n = rbase + r;
          if (n < N) Os[(size_t)n * 128 + col] = bf16r(acc[af][nf][r] + bias);
        }
      }
    }
  }
}

// ---------------- level D: fill_csr + layer-1 gemm, interleaved ----------------

template <int DIN>
__global__ __launch_bounds__(512) void fill_gemm1(
    const int* __restrict__ src, const int* __restrict__ dst,
    const int* __restrict__ rank, const int* __restrict__ rowptr,
    int* __restrict__ csr_src, int E, int epb4,
    const unsigned short* __restrict__ xb, int N,
    const unsigned short* __restrict__ Wt0, const float* __restrict__ B0,
    const unsigned short* __restrict__ Wt1, const float* __restrict__ B1,
    const unsigned short* __restrict__ Wt2, const float* __restrict__ B2,
    const unsigned short* __restrict__ Wt3, const float* __restrict__ B3,
    unsigned short* __restrict__ Qb, unsigned char* __restrict__ KV,
    unsigned short* __restrict__ Os) {
  int b = blockIdx.x;
  int b5 = b / 5, r5 = b - b5 * 5;
  if (r5 == 0) {
    int e4 = E >> 2;
    int end = min((b5 + 1) * epb4, e4);
    for (int i = b5 * epb4 + threadIdx.x; i < end; i += 512) {
      int4 d4 = ((const int4*)dst)[i];
      int4 r4 = ((const int4*)rank)[i];
      int4 s4 = ((const int4*)src)[i];
      csr_src[rowptr[d4.x] + r4.x] = s4.x;
      csr_src[rowptr[d4.y] + r4.y] = s4.y;
      csr_src[rowptr[d4.z] + r4.z] = s4.z;
      csr_src[rowptr[d4.w] + r4.w] = s4.w;
    }
    if (b5 == 0 && threadIdx.x == 0) {
      for (int e = E & ~3; e < E; ++e) csr_src[rowptr[dst[e]] + rank[e]] = src[e];
    }
    return;
  }
  int g = b5 * 4 + r5 - 1;
  gemm4_tile<DIN>(g >> 2, g & 3, threadIdx.x, xb, N, Wt0, B0, Wt1, B1,
                  Wt2, B2, Wt3, B3, Qb, KV, Os);
}

template <int DIN>
__global__ __launch_bounds__(512) void gemm4(
    const unsigned short* __restrict__ xb, int N,
    const unsigned short* __restrict__ Wt0, const float* __restrict__ B0,
    const unsigned short* __restrict__ Wt1, const float* __restrict__ B1,
    const unsigned short* __restrict__ Wt2, const float* __restrict__ B2,
    const unsigned short* __restrict__ Wt3, const float* __restrict__ B3,
    unsigned short* __restrict__ Qb, unsigned char* __restrict__ KV,
    unsigned short* __restrict__ Os) {
  gemm4_tile<DIN>(blockIdx.x, blockIdx.y, threadIdx.x, xb, N, Wt0, B0, Wt1, B1,
                  Wt2, B2, Wt3, B3, Qb, KV, Os);
}

// ---------------- edge aggregation: 4 x 16-lane streams, packed math --------
// Wave = 1 node. Stream g4 = lane>>4 handles edges e = beg+g4+4*it; sublane
// sl = lane&15 owns dims [8*sl, 8*sl+8) as 4 f32x2. Dot = 4 pk-FMA + pair-add;
// 4-level shfl reduce. exp2-domain deferred-max (slack 8). Merges ^16, ^32.
// kv row 256B: k fp8 [0,128), v fp8 [128,256). skip bf16; q bf16 pre-scaled.

template <bool RELU>
__global__ __launch_bounds__(256) void edge_agg4(
    const unsigned short* __restrict__ qb, const unsigned char* __restrict__ kv,
    const int* __restrict__ rowptr, const int* __restrict__ csr_src,
    const unsigned short* __restrict__ skipb, unsigned short* __restrict__ outp,
    int N) {
  int tid = threadIdx.x;
  int lane = tid & 63;
  int wv = tid >> 6;
  int n = blockIdx.x * 4 + wv;
  if (n >= N) return;
  int g4 = lane >> 4;
  int sl = lane & 15;
  uint4 qp = *(const uint4*)&qb[(size_t)n * 128 + 8 * sl];
  f32x2 q2[4];
  q2[0] = bf16_2f(qp.x);
  q2[1] = bf16_2f(qp.y);
  q2[2] = bf16_2f(qp.z);
  q2[3] = bf16_2f(qp.w);
  int beg = rowptr[n];
  int deg = rowptr[n + 1] - beg;
  float m = -1e30f, lsum = 0.f;
  f32x2 acc2[4];
#pragma unroll
  for (int j = 0; j < 4; ++j) acc2[j] = (f32x2){0.f, 0.f};
  int cnt = (deg - g4 + 3) >> 2;
  if (cnt < 0) cnt = 0;
  const int* cp = csr_src + beg + g4;
  unsigned ko = 8u * sl, vo = 128u + 8u * sl;
  uint2 k0 = {0, 0}, k1 = {0, 0};
  uint2 v0 = {0, 0}, v1 = {0, 0};
  if (cnt >= 1) {
    unsigned r = (unsigned)cp[0] * 256u;
    k0 = *(const uint2*)(kv + r + ko);
    v0 = *(const uint2*)(kv + r + vo);
  }
  if (cnt >= 2) {
    unsigned r = (unsigned)cp[4] * 256u;
    k1 = *(const uint2*)(kv + r + ko);
    v1 = *(const uint2*)(kv + r + vo);
  }
  for (int it = 0; it < cnt; ++it) {
    uint2 kc = k0;
    uint2 vc = v0;
    k0 = k1;
    v0 = v1;
    if (it + 2 < cnt) {
      unsigned r = (unsigned)cp[4 * (it + 2)] * 256u;
      k1 = *(const uint2*)(kv + r + ko);
      v1 = *(const uint2*)(kv + r + vo);
    }
    f32x2 kd[4];
    fp8_dec4(kc.x, &kd[0], &kd[1]);
    fp8_dec4(kc.y, &kd[2], &kd[3]);
    f32x2 d2 = q2[0] * kd[0];
    d2 += q2[1] * kd[1];
    d2 += q2[2] * kd[2];
    d2 += q2[3] * kd[3];
    float d = d2[0] + d2[1];
#pragma unroll
    for (int off = 1; off < 16; off <<= 1) d += __shfl_xor(d, off);
    f32x2 w2[4];
    fp8_dec4(vc.x, &w2[0], &w2[1]);
    fp8_dec4(vc.y, &w2[2], &w2[3]);
    if (d > m + 8.f) {        // rare: new max beyond slack -> rescale
      float cf = exp2f(m - d);
      f32x2 cf2 = {cf, cf};
      lsum = lsum * cf + 1.f;
#pragma unroll
      for (int j = 0; j < 4; ++j) acc2[j] = acc2[j] * cf2 + w2[j];
      m = d;
    } else {                  // common: accumulate against stale max
      float ef = exp2f(d - m);
      f32x2 ef2 = {ef, ef};
      lsum += ef;
#pragma unroll
      for (int j = 0; j < 4; ++j) acc2[j] += ef2 * w2[j];
    }
  }
  // merge 4 stream states: ^16 then ^32 (m=-1e30 keeps empty streams NaN-free)
#pragma unroll
  for (int ofs = 16; ofs <= 32; ofs <<= 1) {
    float mo = __shfl_xor(m, ofs);
    float lo = __shfl_xor(lsum, ofs);
    f32x2 ao[4];
#pragma unroll
    for (int j = 0; j < 4; ++j) {
      ao[j][0] = __shfl_xor(acc2[j][0], ofs);
      ao[j][1] = __shfl_xor(acc2[j][1], ofs);
    }
    float M = fmaxf(m, mo);
    float c1 = exp2f(m - M);
    float c2 = exp2f(mo - M);
    f32x2 c12 = {c1, c1}, c22 = {c2, c2};
    lsum = lsum * c1 + lo * c2;
#pragma unroll
    for (int j = 0; j < 4; ++j) acc2[j] = acc2[j] * c12 + ao[j] * c22;
    m = M;
  }
  if (lane < 16) {
    float rl = (deg > 0) ? 1.f / (lsum + 1e-16f) : 0.f;
    f32x2 rl2 = {rl, rl};
    uint4 sp = *(const uint4*)&skipb[(size_t)n * 128 + 8 * sl];
    unsigned sw[4] = {sp.x, sp.y, sp.z, sp.w};
    unsigned ow[4];
#pragma unroll
    for (int j = 0; j < 4; ++j) {
      f32x2 s2 = bf16_2f(sw[j]);
      f32x2 o2 = s2 + acc2[j] * rl2;
      float oa = o2[0], ob = o2[1];
      if (RELU) {
        oa = fmaxf(oa, 0.f);
        ob = fmaxf(ob, 0.f);
      }
      ow[j] = pack_bf16_2(oa, ob);
    }
    uint4 pk = {ow[0], ow[1], ow[2], ow[3]};
    *(uint4*)&outp[(size_t)n * 128 + 8 * sl] = pk;
  }
}

// ---------------- global mean pool (batch sorted, bf16 input) ----------------

__global__ __launch_bounds__(128) void pool_kernel(const unsigned short* __restrict__ h,
                                                   const int* __restrict__ batch,
                                                   float* __restrict__ out, int N) {
  int g = blockIdx.x;
  int lo = 0, hi = N;
  while (lo < hi) { int mid = (lo + hi) >> 1; if (batch[mid] < g) lo = mid + 1; else hi = mid; }
  int s0 = lo;
  hi = N;
  while (lo < hi) { int mid = (lo + hi) >> 1; if (batch[mid] <= g) lo = mid + 1; else hi = mid; }
  int s1 = lo;
  int j = threadIdx.x;
  float acc = 0.f;
  for (int n = s0; n < s1; ++n) acc += bf16f(h[(size_t)n * 128 + j]);
  out[(size_t)g * 128 + j] = acc / fmaxf((float)(s1 - s0), 1.f);
}

// ---------------- launch ----------------

extern "C" void kernel_launch(void* const* d_in, const int* in_sizes, int n_in,
                              void* d_out, int out_size, void* d_ws, size_t ws_size,
                              hipStream_t stream) {
  const float* x = (const float*)d_in[0];
  const int* ei = (const int*)d_in[1];
  const int* batch = (const int*)d_in[2];
  const float* Wq1 = (const float*)d_in[3];
  const float* bq1 = (const float*)d_in[4];
  const float* Wk1 = (const float*)d_in[5];
  const float* bk1 = (const float*)d_in[6];
  const float* Wv1 = (const float*)d_in[7];
  const float* bv1 = (const float*)d_in[8];
  const float* Ws1 = (const float*)d_in[9];
  const float* bs1 = (const float*)d_in[10];
  const float* Wq2 = (const float*)d_in[11];
  const float* bq2 = (const float*)d_in[12];
  const float* Wk2 = (const float*)d_in[13];
  const float* bk2 = (const float*)d_in[14];
  const float* Wv2 = (const float*)d_in[15];
  const float* bv2 = (const float*)d_in[16];
  const float* Ws2 = (const float*)d_in[17];
  const float* bs2 = (const float*)d_in[18];

  int N = in_sizes[0] / D1;  // 50000
  int E = in_sizes[1] / 2;   // 800000
  int NG = out_size / DH;    // 512
  const int* src = ei;
  const int* dst = ei + E;

  char* ws = (char*)d_ws;
  unsigned short* qb = (unsigned short*)ws;  ws += (size_t)N * DH * 2;   // bf16 q (pre-scaled)
  unsigned char* kvb = (unsigned char*)ws;   ws += (size_t)N * 256;     // k fp8 | v fp8
  ws = (char*)(((size_t)ws + 255) & ~(size_t)255);
  unsigned short* sb = (unsigned short*)ws;  ws += (size_t)N * DH * 2;  // bf16 skip
  unsigned short* h1b = (unsigned short*)ws; ws += (size_t)N * DH * 2;  // bf16 h1 / h2
  unsigned short* xb = (unsigned short*)ws;  ws += (size_t)N * D1 * 2;  // bf16 x
  unsigned short* wt[8];
  for (int m = 0; m < 8; ++m) {
    int din = (m < 4) ? 64 : 128;
    wt[m] = (unsigned short*)ws;
    ws += (size_t)128 * din * 2;
  }
  ws = (char*)(((size_t)ws + 255) & ~(size_t)255);
  int* rowptr = (int*)ws; ws += (size_t)(N + 1) * 4;
  ws = (char*)(((size_t)ws + 255) & ~(size_t)255);
  int* deg = (int*)ws;  ws += (size_t)N * 4;
  int* incl = (int*)ws; ws += (size_t)N * 4;
  int* sums = (int*)ws; ws += 1024;
  int* rank = (int*)ws; ws += (size_t)E * 4;
  int* csr = (int*)ws;  ws += (size_t)E * 4;

  int nch = (N + SCHUNK - 1) / SCHUNK;
  int nbHist = ((E >> 2) + 255) / 256;
  int nb = (N + 127) / 128;           // gemm tiles (x4 y)
  int epb4 = ((E >> 2) + nb - 1) / nb;  // int4 edges per fill block

  hipMemsetAsync(deg, 0, (size_t)N * 4, stream);

  // level A: histogram+ranks + weight/x prep (one dispatch)
  hist_prep<<<nbHist + 768, 256, 0, stream>>>(
      dst, deg, rank, E, nbHist, Wq1, Wk1, Wv1, Ws1, Wq2, Wk2, Wv2, Ws2,
      wt[0], wt[1], wt[2], wt[3], wt[4], wt[5], wt[6], wt[7],
      (const float4*)x, (uint2*)xb, N * D1 / 4);
  scan_chunks<<<nch, 256, 0, stream>>>(deg, incl, sums, N);
  finalize_rowptr<<<(N + 255) / 256, 256, 0, stream>>>(incl, sums, rowptr, N);
  // level D: CSR fill + layer-1 gemm, block-interleaved 1:4
  fill_gemm1<D1><<<nb * 5, 512, 0, stream>>>(
      src, dst, rank, rowptr, csr, E, epb4, xb, N,
      wt[0], bq1, wt[1], bk1, wt[2], bv1, wt[3], bs1, qb, kvb, sb);
  edge_agg4<true><<<(N + 3) / 4, 256, 0, stream>>>(
      qb, kvb, rowptr, csr, sb, h1b, N);
  // layer 2
  gemm4<DH><<<dim3(nb, 4), 512, 0, stream>>>(h1b, N, wt[4], bq2, wt[5], bk2,
                                             wt[6], bv2, wt[7], bs2, qb, kvb, sb);
  edge_agg4<false><<<(N + 3) / 4, 256, 0, stream>>>(
      qb, kvb, rowptr, csr, sb, h1b, N);
  // mean pool (bf16 input)
  pool_kernel<<<NG, 128, 0, stream>>>(h1b, batch, (float*)d_out, N);
}